// Round 5
// baseline (177.283 us; speedup 1.0000x reference)
//
#include <hip/hip_runtime.h>
#include <stdint.h>

// Problem constants (fixed by the reference)
#define BN    8192    // batch
#define DK    256     // dim
#define PN    4096    // pairs
#define MAXP  16      // max partners tracked per row (Poisson(1); P(>16) ~ 1e-15)
#define RANK_ASC 6553 // ascending rank of first kept element (top-1639 = 0.8 quantile)

typedef __bf16  bf16_8 __attribute__((ext_vector_type(8)));
typedef __bf16  bf16_4 __attribute__((ext_vector_type(4)));
typedef float   f32x4  __attribute__((ext_vector_type(4)));

__device__ __forceinline__ void gload_lds16(const void* g, void* l) {
  __builtin_amdgcn_global_load_lds(
      (const __attribute__((address_space(1))) unsigned int*)g,
      (__attribute__((address_space(3))) unsigned int*)l, 16, 0, 0);
}

// ---------------------------------------------------------------- prep
__global__ void prep_clear_kernel(int* pcount, int* rowlist, int* cnt) {
  const int i = blockIdx.x * 256 + threadIdx.x;
  if (i < BN) { pcount[i] = 0; rowlist[i] = 0; }
  if (i == 0) cnt[0] = 0;
}

__global__ void prep_pairs_kernel(const int2* __restrict__ pairs,
                                  int* pcount, int* partners) {
  const int p = blockIdx.x * 256 + threadIdx.x;
  if (p >= PN) return;
  int2 pr = pairs[p];
  int ix = atomicAdd(&pcount[pr.x], 1);
  if (ix < MAXP) partners[pr.x * MAXP + ix] = pr.y;
  int iy = atomicAdd(&pcount[pr.y], 1);
  if (iy < MAXP) partners[pr.y * MAXP + iy] = pr.x;
}

__global__ void prep_compact_kernel(const int* __restrict__ pcount,
                                    int* rowlist, int* cnt) {
  const int i = blockIdx.x * 256 + threadIdx.x;
  if (i < BN && pcount[i] > 0) {
    int pos = atomicAdd(cnt, 1);
    rowlist[pos] = i;
  }
}

// ---------------------------------------------------------------- normalize
__global__ void __launch_bounds__(256) normalize_kernel(
    const float* __restrict__ X, float* __restrict__ E, __bf16* __restrict__ Ebf) {
  const int tid  = threadIdx.x;
  const int lane = tid & 63;
  const int w    = tid >> 6;
  const int row  = blockIdx.x * 4 + w;
  float4 x = ((const float4*)(X + (size_t)row * DK))[lane];
  float ss = x.x * x.x + x.y * x.y + x.z * x.z + x.w * x.w;
  #pragma unroll
  for (int o = 32; o; o >>= 1) ss += __shfl_xor(ss, o);
  float nrm = fmaxf(sqrtf(ss), 1e-8f);
  float4 e;
  e.x = x.x / nrm; e.y = x.y / nrm; e.z = x.z / nrm; e.w = x.w / nrm;
  ((float4*)(E + (size_t)row * DK))[lane] = e;
  bf16_4 b;
  b[0] = (__bf16)e.x; b[1] = (__bf16)e.y; b[2] = (__bf16)e.z; b[3] = (__bf16)e.w;
  *(bf16_4*)(Ebf + (size_t)row * DK + lane * 4) = b;
}

// ---------------------------------------------------------------- pos values
__global__ void __launch_bounds__(256) pos_kernel(
    const float* __restrict__ E, const int2* __restrict__ pairs, float* __restrict__ pos) {
  const int tid  = threadIdx.x;
  const int lane = tid & 63;
  const int w    = tid >> 6;
  const int p    = blockIdx.x * 4 + w;
  int2 pr = pairs[p];
  float4 a = ((const float4*)(E + (size_t)pr.x * DK))[lane];
  float4 b = ((const float4*)(E + (size_t)pr.y * DK))[lane];
  float d = a.x * b.x + a.y * b.y + a.z * b.z + a.w * b.w;
  #pragma unroll
  for (int o = 32; o; o >>= 1) d += __shfl_xor(d, o);
  if (lane == 0) pos[p] = __expf(5.0f * d);
}

// ------------------------------------------------ parallel bin finder (256 bins)
__device__ __forceinline__ void find_bin_256(const unsigned* hist, int rank,
                                             int* sh, unsigned* wtot) {
  const int tid = threadIdx.x, lane = tid & 63, w = tid >> 6;
  unsigned x = hist[tid];
  unsigned pref = x;
  #pragma unroll
  for (int o = 1; o < 64; o <<= 1) {
    unsigned y = __shfl_up(pref, o);
    if (lane >= o) pref += y;
  }
  if (lane == 63) wtot[w] = pref;
  __syncthreads();
  unsigned woff = 0;
  for (int i = 0; i < w; ++i) woff += wtot[i];
  unsigned incl = pref + woff, excl = incl - x;
  if ((unsigned)rank >= excl && (unsigned)rank < incl) { sh[0] = tid; sh[1] = rank - (int)excl; }
  __syncthreads();
}

// ---------------------------------------------------------------- GEMM + exp -> fp8
// C = exp(5 * E[rowlist[r]] . E[c]) packed fp8 e4m3, interleaved layout:
// dword at [rowgroup][col] holds rows 4*rowgroup..+3 at that col (byte = row%4).
// 128x128 tile, BK=32, mfma 16x16x32 bf16, global_load_lds(16B) staging.
__global__ void __launch_bounds__(256) gemm_exp_kernel(
    const __bf16* __restrict__ E, const int* __restrict__ rowlist,
    const int* __restrict__ countp, uint32_t* __restrict__ out4) {
  if ((int)blockIdx.y * 128 >= *countp) return;   // beyond compacted rows
  __shared__ __align__(16) __bf16 sA[128 * 32];
  __shared__ __align__(16) __bf16 sB[128 * 32];
  const int tid  = threadIdx.x;
  const int lane = tid & 63;
  const int w    = tid >> 6;
  const int wm   = w >> 1, wn = w & 1;
  const int trow = blockIdx.y * 128;   // compact-row base
  const int tcol = blockIdx.x * 128;   // global col base
  const int r0   = tid >> 2;           // rows 0..63
  const int seg  = tid & 3;            // 8-bf16 segment of the 32-wide K slice

  const int ga0 = rowlist[trow + r0];
  const int ga1 = rowlist[trow + 64 + r0];
  const __bf16* pa0 = E + (size_t)ga0 * DK + seg * 8;
  const __bf16* pa1 = E + (size_t)ga1 * DK + seg * 8;
  const __bf16* pb0 = E + (size_t)(tcol + r0) * DK + seg * 8;
  const __bf16* pb1 = E + (size_t)(tcol + 64 + r0) * DK + seg * 8;
  __bf16* la0 = &sA[tid * 8];          // r0*32 + seg*8 == tid*8
  __bf16* la1 = &sA[2048 + tid * 8];
  __bf16* lb0 = &sB[tid * 8];
  __bf16* lb1 = &sB[2048 + tid * 8];

  f32x4 acc[4][4];
  #pragma unroll
  for (int i = 0; i < 4; ++i)
    #pragma unroll
    for (int j = 0; j < 4; ++j) {
      f32x4 z = {0.f, 0.f, 0.f, 0.f};
      acc[i][j] = z;
    }

  for (int kt = 0; kt < 8; ++kt) {
    const int k0 = kt * 32;
    __syncthreads();
    gload_lds16(pa0 + k0, la0);
    gload_lds16(pa1 + k0, la1);
    gload_lds16(pb0 + k0, lb0);
    gload_lds16(pb1 + k0, lb1);
    __syncthreads();
    bf16_8 af[4], bfg[4];
    #pragma unroll
    for (int t = 0; t < 4; ++t) {
      af[t]  = *(const bf16_8*)&sA[(wm * 64 + t * 16 + (lane & 15)) * 32 + (lane >> 4) * 8];
      bfg[t] = *(const bf16_8*)&sB[(wn * 64 + t * 16 + (lane & 15)) * 32 + (lane >> 4) * 8];
    }
    #pragma unroll
    for (int i = 0; i < 4; ++i)
      #pragma unroll
      for (int j = 0; j < 4; ++j)
        acc[i][j] = __builtin_amdgcn_mfma_f32_16x16x32_bf16(af[i], bfg[j], acc[i][j], 0, 0, 0);
  }

  // epilogue: acc[i][j] = rows crow+i*16..+3 (consecutive, crow%4==0) at one col
  const int crow = trow + wm * 64 + (lane >> 4) * 4;
  const int ccol = tcol + wn * 64 + (lane & 15);
  #pragma unroll
  for (int i = 0; i < 4; ++i) {
    const int gidx = (crow + i * 16) >> 2;
    #pragma unroll
    for (int j = 0; j < 4; ++j) {
      const int col = ccol + j * 16;
      float e0 = __expf(acc[i][j][0] * 5.0f);
      float e1 = __expf(acc[i][j][1] * 5.0f);
      float e2 = __expf(acc[i][j][2] * 5.0f);
      float e3 = __expf(acc[i][j][3] * 5.0f);
      int u = __builtin_amdgcn_cvt_pk_fp8_f32(e0, e1, 0, false);
      u     = __builtin_amdgcn_cvt_pk_fp8_f32(e2, e3, u, true);
      out4[(size_t)gidx * BN + col] = (uint32_t)u;
    }
  }
}

// ---------------------------------------------------------------- row stats (fp8)
// One block per group of 4 compacted rows. fp8 byte == radix bin, so ONE
// histogram pass gives an exact select on quantized values:
// S = sum_{bin>b} cnt*val + need*val(b)  (all values within a bin identical).
__global__ void __launch_bounds__(256) row_stats4_kernel(
    const uint32_t* __restrict__ expc4, const int* __restrict__ rowlist,
    const int* __restrict__ countp, const int* __restrict__ pcount,
    const int* __restrict__ partners, float* __restrict__ S) {
  __shared__ unsigned hist[4][4][256];   // [wave][r4][bin] = 16 KB
  __shared__ unsigned total[4][256];     // 4 KB
  __shared__ int plist[4][MAXP + 1];
  __shared__ int npl[4];
  __shared__ int growl[4];
  __shared__ int sh[2];
  __shared__ unsigned wtot[4];
  __shared__ float redf[4];
  const int g = blockIdx.x;
  const int cnt = *countp;
  if (g * 4 >= cnt) return;
  const int tid = threadIdx.x, lane = tid & 63, w = tid >> 6;

  // coalesced 32 KB load; uint4 #t covers cols 4t..4t+3, dword=col, byte=row%4
  uint4 rv[8];
  const uint4* src = (const uint4*)(expc4 + (size_t)g * BN);
  #pragma unroll
  for (int q = 0; q < 8; ++q) rv[q] = src[q * 256 + tid];

  if (tid < 4) {
    int rr = g * 4 + tid;
    int grow = (rr < cnt) ? rowlist[rr] : -1;
    growl[tid] = grow;
    int np = 0;
    if (grow >= 0) {
      np = pcount[grow]; if (np > MAXP) np = MAXP;
      for (int e = 0; e < np; ++e) plist[tid][e] = partners[grow * MAXP + e];
      plist[tid][np] = grow;   // diagonal
      np++;
    }
    npl[tid] = np;
  }
  #pragma unroll
  for (int k = 0; k < 16; ++k) ((unsigned*)hist)[k * 256 + tid] = 0;
  __syncthreads();

  // mask partner/diagonal columns (zero the byte -> bin 0, never selected)
  #pragma unroll
  for (int r4 = 0; r4 < 4; ++r4) {
    const int np = npl[r4];
    for (int e = 0; e < np; ++e) {
      int c = plist[r4][e];
      int t = c >> 2;
      if ((t & 255) == tid) {
        unsigned* wp = (unsigned*)&rv[t >> 8];
        wp[c & 3] &= ~(0xFFu << (r4 * 8));
      }
    }
  }

  // single histogram pass, per-wave privatized, 4 rows at once
  unsigned* h = (unsigned*)hist[w];
  #pragma unroll
  for (int q = 0; q < 8; ++q) {
    #pragma unroll
    for (int word = 0; word < 4; ++word) {
      unsigned dw = ((const unsigned*)&rv[q])[word];
      atomicAdd(&h[0 * 256 + (dw & 255u)], 1u);
      atomicAdd(&h[1 * 256 + ((dw >> 8) & 255u)], 1u);
      atomicAdd(&h[2 * 256 + ((dw >> 16) & 255u)], 1u);
      atomicAdd(&h[3 * 256 + (dw >> 24)], 1u);
    }
  }
  __syncthreads();
  #pragma unroll
  for (int r4 = 0; r4 < 4; ++r4)
    total[r4][tid] = hist[0][r4][tid] + hist[1][r4][tid] + hist[2][r4][tid] + hist[3][r4][tid];
  __syncthreads();

  // decode fp8 e4m3 code 'tid' (only positive codes occur in valid rows)
  const int Ee = (tid >> 3) & 15, Mm = tid & 7;
  const float val = (Ee == 0) ? ldexpf((float)Mm, -9) : ldexpf((float)(8 + Mm), Ee - 10);

  for (int r4 = 0; r4 < 4; ++r4) {
    find_bin_256(total[r4], RANK_ASC, sh, wtot);
    const int b    = sh[0];
    const int need = (int)total[r4][b] - sh[1];
    float contrib = (tid > b) ? (float)total[r4][tid] * val
                  : (tid == b) ? (float)need * val : 0.f;
    #pragma unroll
    for (int o = 32; o; o >>= 1) contrib += __shfl_xor(contrib, o);
    __syncthreads();
    if (lane == 0) redf[w] = contrib;
    __syncthreads();
    if (tid == 0 && growl[r4] >= 0)
      S[growl[r4]] = redf[0] + redf[1] + redf[2] + redf[3];
    __syncthreads();
  }
}

// ---------------------------------------------------------------- finale
// Single block: exact radix select of pos rank 819 -> thr; active sums over pos;
// pair terms over S; factorized combine:
// loss = (n*T - 2P*sl + sp*U - 0.5*sp2*V) / (2P), from
// log1p(S/p) = logS - logp + p/S - p^2/(2S^2) + O((p/S)^3), p/S <~ 3e-4.
__device__ __forceinline__ float block_sum4(float x, float* red4) {
  const int lane = threadIdx.x & 63, w = threadIdx.x >> 6;
  #pragma unroll
  for (int o = 32; o; o >>= 1) x += __shfl_xor(x, o);
  __syncthreads();
  if (lane == 0) red4[w] = x;
  __syncthreads();
  return red4[0] + red4[1] + red4[2] + red4[3];
}

__global__ void __launch_bounds__(256) finale_kernel(
    const float* __restrict__ pos, const int2* __restrict__ pairs,
    const float* __restrict__ S, float* __restrict__ out) {
  __shared__ uint32_t v[PN];
  __shared__ unsigned hist[256];
  __shared__ int sh[2];
  __shared__ unsigned wtot[4];
  __shared__ float red4[4];
  const int tid = threadIdx.x;
  for (int i = tid; i < PN; i += 256) v[i] = ((const uint32_t*)pos)[i];
  __syncthreads();

  // exact radix select rank 819 (0.2 * 4095) over positive fp32 bits
  int rank = 819;
  uint32_t prefix = 0;
  for (int pass = 0; pass < 4; ++pass) {
    const int shift = 24 - pass * 8;
    hist[tid] = 0;
    __syncthreads();
    for (int i = tid; i < PN; i += 256) {
      uint32_t x = v[i];
      bool match = (pass == 0) || ((x >> (shift + 8)) == (prefix >> (shift + 8)));
      if (match) atomicAdd(&hist[(x >> shift) & 255u], 1u);
    }
    __syncthreads();
    find_bin_256(hist, rank, sh, wtot);
    prefix |= ((uint32_t)sh[0]) << shift;
    rank = sh[1];
    __syncthreads();
  }
  float thr; __builtin_memcpy(&thr, &prefix, 4);

  // active sums over pos (from LDS)
  float n = 0.f, sl = 0.f, sp = 0.f, sp2 = 0.f;
  for (int r = tid; r < PN; r += 256) {
    float p; uint32_t b = v[r]; __builtin_memcpy(&p, &b, 4);
    if (p <= thr) { n += 1.f; sl += __logf(p); sp += p; sp2 += p * p; }
  }
  // pair terms over S
  float t = 0.f, u = 0.f, vv = 0.f;
  for (int c = tid; c < PN; c += 256) {
    int2 pr = pairs[c];
    float s1 = S[pr.x], s2 = S[pr.y];
    float i1 = 1.f / s1, i2 = 1.f / s2;
    t += __logf(s1) + __logf(s2);
    u += i1 + i2;
    vv += i1 * i1 + i2 * i2;
  }
  const float N  = block_sum4(n, red4);
  const float SL = block_sum4(sl, red4);
  const float SP = block_sum4(sp, red4);
  const float SP2= block_sum4(sp2, red4);
  const float T  = block_sum4(t, red4);
  const float U  = block_sum4(u, red4);
  const float V  = block_sum4(vv, red4);
  if (tid == 0) {
    double num = (double)N * T - 2.0 * (double)PN * (double)SL
               + (double)SP * U - 0.5 * (double)SP2 * V;
    out[0] = (float)(num / (2.0 * (double)PN));
  }
}

// ---------------------------------------------------------------- launch
extern "C" void kernel_launch(void* const* d_in, const int* in_sizes, int n_in,
                              void* d_out, int out_size, void* d_ws, size_t ws_size,
                              hipStream_t stream) {
  const float* emb  = (const float*)d_in[0];
  const int2* pairs = (const int2*)d_in[1];
  float* out = (float*)d_out;

  char* w = (char*)d_ws;
  size_t off = 0;
  float*    E     = (float*)(w + off);    off += (size_t)BN * DK * 4;      // 8 MB
  __bf16*   Ebf   = (__bf16*)(w + off);   off += (size_t)BN * DK * 2;      // 4 MB
  float*    S     = (float*)(w + off);    off += (size_t)BN * 4;
  float*    pos   = (float*)(w + off);    off += (size_t)PN * 4;
  int*      pcnt  = (int*)(w + off);      off += (size_t)BN * 4;
  int*      parts = (int*)(w + off);      off += (size_t)BN * MAXP * 4;    // 512 KB
  int*      rlist = (int*)(w + off);      off += (size_t)BN * 4;
  int*      cnt   = (int*)(w + off);      off += 256;
  uint32_t* expc4 = (uint32_t*)(w + off); off += (size_t)(BN / 4) * BN * 4; // 67 MB worst case

  prep_clear_kernel<<<BN / 256, 256, 0, stream>>>(pcnt, rlist, cnt);
  normalize_kernel<<<BN / 4, 256, 0, stream>>>(emb, E, Ebf);
  prep_pairs_kernel<<<PN / 256, 256, 0, stream>>>(pairs, pcnt, parts);
  prep_compact_kernel<<<BN / 256, 256, 0, stream>>>(pcnt, rlist, cnt);
  pos_kernel<<<PN / 4, 256, 0, stream>>>(E, pairs, pos);
  gemm_exp_kernel<<<dim3(BN / 128, BN / 128), 256, 0, stream>>>(Ebf, rlist, cnt, expc4);
  row_stats4_kernel<<<BN / 4, 256, 0, stream>>>(expc4, rlist, cnt, pcnt, parts, S);
  finale_kernel<<<1, 256, 0, stream>>>(pos, pairs, S, out);
}

// Round 6
// 166.088 us; speedup vs baseline: 1.0674x; 1.0674x over previous
//
#include <hip/hip_runtime.h>
#include <stdint.h>

// Problem constants (fixed by the reference)
#define BN    8192    // batch
#define DK    256     // dim
#define PN    4096    // pairs
#define MAXP  16      // max partners tracked per row (Poisson(1); P(>16) ~ 1e-15)
#define RANK_ASC 6553 // ascending rank of first kept element (top-1639 = 0.8 quantile)
#define QSTEP 0.02f   // logit quantization step: code = round(5*cos/QSTEP)+128 in [1,255]
#define QINV  50.0f   // 1/QSTEP

typedef __bf16  bf16_8 __attribute__((ext_vector_type(8)));
typedef __bf16  bf16_4 __attribute__((ext_vector_type(4)));
typedef float   f32x4  __attribute__((ext_vector_type(4)));

__device__ __forceinline__ void gload_lds16(const void* g, void* l) {
  __builtin_amdgcn_global_load_lds(
      (const __attribute__((address_space(1))) unsigned int*)g,
      (__attribute__((address_space(3))) unsigned int*)l, 16, 0, 0);
}

// ---------------------------------------------------------------- prep
__global__ void prep_clear_kernel(int* pcount, int* rowlist, int* cnt) {
  const int i = blockIdx.x * 256 + threadIdx.x;
  if (i < BN) { pcount[i] = 0; rowlist[i] = 0; }
  if (i == 0) cnt[0] = 0;
}

__global__ void prep_pairs_kernel(const int2* __restrict__ pairs,
                                  int* pcount, int* partners) {
  const int p = blockIdx.x * 256 + threadIdx.x;
  if (p >= PN) return;
  int2 pr = pairs[p];
  int ix = atomicAdd(&pcount[pr.x], 1);
  if (ix < MAXP) partners[pr.x * MAXP + ix] = pr.y;
  int iy = atomicAdd(&pcount[pr.y], 1);
  if (iy < MAXP) partners[pr.y * MAXP + iy] = pr.x;
}

__global__ void prep_compact_kernel(const int* __restrict__ pcount,
                                    int* rowlist, int* cnt) {
  const int i = blockIdx.x * 256 + threadIdx.x;
  if (i < BN && pcount[i] > 0) {
    int pos = atomicAdd(cnt, 1);
    rowlist[pos] = i;
  }
}

// ---------------------------------------------------------------- normalize
__global__ void __launch_bounds__(256) normalize_kernel(
    const float* __restrict__ X, float* __restrict__ E, __bf16* __restrict__ Ebf) {
  const int tid  = threadIdx.x;
  const int lane = tid & 63;
  const int w    = tid >> 6;
  const int row  = blockIdx.x * 4 + w;
  float4 x = ((const float4*)(X + (size_t)row * DK))[lane];
  float ss = x.x * x.x + x.y * x.y + x.z * x.z + x.w * x.w;
  #pragma unroll
  for (int o = 32; o; o >>= 1) ss += __shfl_xor(ss, o);
  float nrm = fmaxf(sqrtf(ss), 1e-8f);
  float4 e;
  e.x = x.x / nrm; e.y = x.y / nrm; e.z = x.z / nrm; e.w = x.w / nrm;
  ((float4*)(E + (size_t)row * DK))[lane] = e;
  bf16_4 b;
  b[0] = (__bf16)e.x; b[1] = (__bf16)e.y; b[2] = (__bf16)e.z; b[3] = (__bf16)e.w;
  *(bf16_4*)(Ebf + (size_t)row * DK + lane * 4) = b;
}

// ---------------------------------------------------------------- pos values
__global__ void __launch_bounds__(256) pos_kernel(
    const float* __restrict__ E, const int2* __restrict__ pairs, float* __restrict__ pos) {
  const int tid  = threadIdx.x;
  const int lane = tid & 63;
  const int w    = tid >> 6;
  const int p    = blockIdx.x * 4 + w;
  int2 pr = pairs[p];
  float4 a = ((const float4*)(E + (size_t)pr.x * DK))[lane];
  float4 b = ((const float4*)(E + (size_t)pr.y * DK))[lane];
  float d = a.x * b.x + a.y * b.y + a.z * b.z + a.w * b.w;
  #pragma unroll
  for (int o = 32; o; o >>= 1) d += __shfl_xor(d, o);
  if (lane == 0) pos[p] = __expf(5.0f * d);
}

// ------------------------------------------------ parallel bin finder (256 bins)
__device__ __forceinline__ void find_bin_256(const unsigned* hist, int rank,
                                             int* sh, unsigned* wtot) {
  const int tid = threadIdx.x, lane = tid & 63, w = tid >> 6;
  unsigned x = hist[tid];
  unsigned pref = x;
  #pragma unroll
  for (int o = 1; o < 64; o <<= 1) {
    unsigned y = __shfl_up(pref, o);
    if (lane >= o) pref += y;
  }
  if (lane == 63) wtot[w] = pref;
  __syncthreads();
  unsigned woff = 0;
  for (int i = 0; i < w; ++i) woff += wtot[i];
  unsigned incl = pref + woff, excl = incl - x;
  if ((unsigned)rank >= excl && (unsigned)rank < incl) { sh[0] = tid; sh[1] = rank - (int)excl; }
  __syncthreads();
}

// ---------------------------------------------------------------- GEMM -> logit codes
// code[r][c] = clamp(round(5*cos * 50) + 128, 1, 255), 0 reserved for masked.
// Monotone in cos => rank-exact; decode in row_stats is exp((code-128)*0.02).
// Interleaved layout: dword at [rowgroup][col] = rows 4*rowgroup..+3 (byte=row%4).
// 128x128 tile, BK=32, mfma 16x16x32 bf16, global_load_lds(16B) staging.
__global__ void __launch_bounds__(256) gemm_code_kernel(
    const __bf16* __restrict__ E, const int* __restrict__ rowlist,
    const int* __restrict__ countp, uint32_t* __restrict__ out4) {
  if ((int)blockIdx.y * 128 >= *countp) return;   // beyond compacted rows
  __shared__ __align__(16) __bf16 sA[128 * 32];
  __shared__ __align__(16) __bf16 sB[128 * 32];
  const int tid  = threadIdx.x;
  const int lane = tid & 63;
  const int w    = tid >> 6;
  const int wm   = w >> 1, wn = w & 1;
  const int trow = blockIdx.y * 128;   // compact-row base
  const int tcol = blockIdx.x * 128;   // global col base
  const int r0   = tid >> 2;           // rows 0..63
  const int seg  = tid & 3;            // 8-bf16 segment of the 32-wide K slice

  const int ga0 = rowlist[trow + r0];
  const int ga1 = rowlist[trow + 64 + r0];
  const __bf16* pa0 = E + (size_t)ga0 * DK + seg * 8;
  const __bf16* pa1 = E + (size_t)ga1 * DK + seg * 8;
  const __bf16* pb0 = E + (size_t)(tcol + r0) * DK + seg * 8;
  const __bf16* pb1 = E + (size_t)(tcol + 64 + r0) * DK + seg * 8;
  __bf16* la0 = &sA[tid * 8];          // r0*32 + seg*8 == tid*8
  __bf16* la1 = &sA[2048 + tid * 8];
  __bf16* lb0 = &sB[tid * 8];
  __bf16* lb1 = &sB[2048 + tid * 8];

  f32x4 acc[4][4];
  #pragma unroll
  for (int i = 0; i < 4; ++i)
    #pragma unroll
    for (int j = 0; j < 4; ++j) {
      f32x4 z = {0.f, 0.f, 0.f, 0.f};
      acc[i][j] = z;
    }

  for (int kt = 0; kt < 8; ++kt) {
    const int k0 = kt * 32;
    __syncthreads();
    gload_lds16(pa0 + k0, la0);
    gload_lds16(pa1 + k0, la1);
    gload_lds16(pb0 + k0, lb0);
    gload_lds16(pb1 + k0, lb1);
    __syncthreads();
    bf16_8 af[4], bfg[4];
    #pragma unroll
    for (int t = 0; t < 4; ++t) {
      af[t]  = *(const bf16_8*)&sA[(wm * 64 + t * 16 + (lane & 15)) * 32 + (lane >> 4) * 8];
      bfg[t] = *(const bf16_8*)&sB[(wn * 64 + t * 16 + (lane & 15)) * 32 + (lane >> 4) * 8];
    }
    #pragma unroll
    for (int i = 0; i < 4; ++i)
      #pragma unroll
      for (int j = 0; j < 4; ++j)
        acc[i][j] = __builtin_amdgcn_mfma_f32_16x16x32_bf16(af[i], bfg[j], acc[i][j], 0, 0, 0);
  }

  // epilogue: acc[i][j] = 4 consecutive compact rows (crow%4==0) at one col
  const int crow = trow + wm * 64 + (lane >> 4) * 4;
  const int ccol = tcol + wn * 64 + (lane & 15);
  #pragma unroll
  for (int i = 0; i < 4; ++i) {
    const int gidx = (crow + i * 16) >> 2;
    #pragma unroll
    for (int j = 0; j < 4; ++j) {
      const int col = ccol + j * 16;
      uint32_t u = 0;
      #pragma unroll
      for (int r = 0; r < 4; ++r) {
        // 5*cos * QINV = acc * 250
        int c = (int)rintf(fmaf(acc[i][j][r], 250.0f, 128.0f));
        c = c < 1 ? 1 : (c > 255 ? 255 : c);
        u |= (uint32_t)c << (8 * r);
      }
      out4[(size_t)gidx * BN + col] = u;
    }
  }
}

// ---------------------------------------------------------------- row stats (codes)
// One block per group of 4 compacted rows. Code byte == radix bin (uniform in
// logit space -> ~100 occupied bins, low atomic contention). One histogram
// pass gives an exact select on quantized values:
// S = sum_{bin>b} cnt*val(bin) + need*val(b).
__global__ void __launch_bounds__(256) row_stats4_kernel(
    const uint32_t* __restrict__ expc4, const int* __restrict__ rowlist,
    const int* __restrict__ countp, const int* __restrict__ pcount,
    const int* __restrict__ partners, float* __restrict__ S) {
  __shared__ unsigned hist[4][4][256];   // [wave][r4][bin] = 16 KB
  __shared__ unsigned total[4][256];     // 4 KB
  __shared__ int plist[4][MAXP + 1];
  __shared__ int npl[4];
  __shared__ int growl[4];
  __shared__ int sh[2];
  __shared__ unsigned wtot[4];
  __shared__ float redf[4];
  const int g = blockIdx.x;
  const int cnt = *countp;
  if (g * 4 >= cnt) return;
  const int tid = threadIdx.x, lane = tid & 63, w = tid >> 6;

  // coalesced 32 KB load; uint4 #t covers cols 4t..4t+3, dword=col, byte=row%4
  uint4 rv[8];
  const uint4* src = (const uint4*)(expc4 + (size_t)g * BN);
  #pragma unroll
  for (int q = 0; q < 8; ++q) rv[q] = src[q * 256 + tid];

  if (tid < 4) {
    int rr = g * 4 + tid;
    int grow = (rr < cnt) ? rowlist[rr] : -1;
    growl[tid] = grow;
    int np = 0;
    if (grow >= 0) {
      np = pcount[grow]; if (np > MAXP) np = MAXP;
      for (int e = 0; e < np; ++e) plist[tid][e] = partners[grow * MAXP + e];
      plist[tid][np] = grow;   // diagonal
      np++;
    }
    npl[tid] = np;
  }
  #pragma unroll
  for (int k = 0; k < 16; ++k) ((unsigned*)hist)[k * 256 + tid] = 0;
  __syncthreads();

  // mask partner/diagonal columns (zero the byte -> bin 0, never selected)
  #pragma unroll
  for (int r4 = 0; r4 < 4; ++r4) {
    const int np = npl[r4];
    for (int e = 0; e < np; ++e) {
      int c = plist[r4][e];
      int t = c >> 2;
      if ((t & 255) == tid) {
        unsigned* wp = (unsigned*)&rv[t >> 8];
        wp[c & 3] &= ~(0xFFu << (r4 * 8));
      }
    }
  }

  // single histogram pass, per-wave privatized, 4 rows at once
  unsigned* h = (unsigned*)hist[w];
  #pragma unroll
  for (int q = 0; q < 8; ++q) {
    #pragma unroll
    for (int word = 0; word < 4; ++word) {
      unsigned dw = ((const unsigned*)&rv[q])[word];
      atomicAdd(&h[0 * 256 + (dw & 255u)], 1u);
      atomicAdd(&h[1 * 256 + ((dw >> 8) & 255u)], 1u);
      atomicAdd(&h[2 * 256 + ((dw >> 16) & 255u)], 1u);
      atomicAdd(&h[3 * 256 + (dw >> 24)], 1u);
    }
  }
  __syncthreads();
  #pragma unroll
  for (int r4 = 0; r4 < 4; ++r4)
    total[r4][tid] = hist[0][r4][tid] + hist[1][r4][tid] + hist[2][r4][tid] + hist[3][r4][tid];
  __syncthreads();

  // decode logit code 'tid': val = exp((tid-128)*QSTEP)
  const float val = __expf((float)(tid - 128) * QSTEP);

  for (int r4 = 0; r4 < 4; ++r4) {
    find_bin_256(total[r4], RANK_ASC, sh, wtot);
    const int b    = sh[0];
    const int need = (int)total[r4][b] - sh[1];
    float contrib = (tid > b) ? (float)total[r4][tid] * val
                  : (tid == b) ? (float)need * val : 0.f;
    #pragma unroll
    for (int o = 32; o; o >>= 1) contrib += __shfl_xor(contrib, o);
    __syncthreads();
    if (lane == 0) redf[w] = contrib;
    __syncthreads();
    if (tid == 0 && growl[r4] >= 0)
      S[growl[r4]] = redf[0] + redf[1] + redf[2] + redf[3];
    __syncthreads();
  }
}

// ---------------------------------------------------------------- finale
// Single block: exact radix select of pos rank 819 -> thr; active sums over pos;
// pair terms over S; factorized combine:
// loss = (n*T - 2P*sl + sp*U - 0.5*sp2*V) / (2P), from
// log1p(S/p) = logS - logp + p/S - p^2/(2S^2) + O((p/S)^3), p/S <~ 3e-4.
__device__ __forceinline__ float block_sum4(float x, float* red4) {
  const int lane = threadIdx.x & 63, w = threadIdx.x >> 6;
  #pragma unroll
  for (int o = 32; o; o >>= 1) x += __shfl_xor(x, o);
  __syncthreads();
  if (lane == 0) red4[w] = x;
  __syncthreads();
  return red4[0] + red4[1] + red4[2] + red4[3];
}

__global__ void __launch_bounds__(256) finale_kernel(
    const float* __restrict__ pos, const int2* __restrict__ pairs,
    const float* __restrict__ S, float* __restrict__ out) {
  __shared__ uint32_t v[PN];
  __shared__ unsigned hist[256];
  __shared__ int sh[2];
  __shared__ unsigned wtot[4];
  __shared__ float red4[4];
  const int tid = threadIdx.x;
  for (int i = tid; i < PN; i += 256) v[i] = ((const uint32_t*)pos)[i];
  __syncthreads();

  // exact radix select rank 819 (0.2 * 4095) over positive fp32 bits
  int rank = 819;
  uint32_t prefix = 0;
  for (int pass = 0; pass < 4; ++pass) {
    const int shift = 24 - pass * 8;
    hist[tid] = 0;
    __syncthreads();
    for (int i = tid; i < PN; i += 256) {
      uint32_t x = v[i];
      bool match = (pass == 0) || ((x >> (shift + 8)) == (prefix >> (shift + 8)));
      if (match) atomicAdd(&hist[(x >> shift) & 255u], 1u);
    }
    __syncthreads();
    find_bin_256(hist, rank, sh, wtot);
    prefix |= ((uint32_t)sh[0]) << shift;
    rank = sh[1];
    __syncthreads();
  }
  float thr; __builtin_memcpy(&thr, &prefix, 4);

  // active sums over pos (from LDS)
  float n = 0.f, sl = 0.f, sp = 0.f, sp2 = 0.f;
  for (int r = tid; r < PN; r += 256) {
    float p; uint32_t b = v[r]; __builtin_memcpy(&p, &b, 4);
    if (p <= thr) { n += 1.f; sl += __logf(p); sp += p; sp2 += p * p; }
  }
  // pair terms over S
  float t = 0.f, u = 0.f, vv = 0.f;
  for (int c = tid; c < PN; c += 256) {
    int2 pr = pairs[c];
    float s1 = S[pr.x], s2 = S[pr.y];
    float i1 = 1.f / s1, i2 = 1.f / s2;
    t += __logf(s1) + __logf(s2);
    u += i1 + i2;
    vv += i1 * i1 + i2 * i2;
  }
  const float N  = block_sum4(n, red4);
  const float SL = block_sum4(sl, red4);
  const float SP = block_sum4(sp, red4);
  const float SP2= block_sum4(sp2, red4);
  const float T  = block_sum4(t, red4);
  const float U  = block_sum4(u, red4);
  const float V  = block_sum4(vv, red4);
  if (tid == 0) {
    double num = (double)N * T - 2.0 * (double)PN * (double)SL
               + (double)SP * U - 0.5 * (double)SP2 * V;
    out[0] = (float)(num / (2.0 * (double)PN));
  }
}

// ---------------------------------------------------------------- launch
extern "C" void kernel_launch(void* const* d_in, const int* in_sizes, int n_in,
                              void* d_out, int out_size, void* d_ws, size_t ws_size,
                              hipStream_t stream) {
  const float* emb  = (const float*)d_in[0];
  const int2* pairs = (const int2*)d_in[1];
  float* out = (float*)d_out;

  char* w = (char*)d_ws;
  size_t off = 0;
  float*    E     = (float*)(w + off);    off += (size_t)BN * DK * 4;      // 8 MB
  __bf16*   Ebf   = (__bf16*)(w + off);   off += (size_t)BN * DK * 2;      // 4 MB
  float*    S     = (float*)(w + off);    off += (size_t)BN * 4;
  float*    pos   = (float*)(w + off);    off += (size_t)PN * 4;
  int*      pcnt  = (int*)(w + off);      off += (size_t)BN * 4;
  int*      parts = (int*)(w + off);      off += (size_t)BN * MAXP * 4;    // 512 KB
  int*      rlist = (int*)(w + off);      off += (size_t)BN * 4;
  int*      cnt   = (int*)(w + off);      off += 256;
  uint32_t* expc4 = (uint32_t*)(w + off); off += (size_t)(BN / 4) * BN * 4; // 67 MB worst case

  prep_clear_kernel<<<BN / 256, 256, 0, stream>>>(pcnt, rlist, cnt);
  normalize_kernel<<<BN / 4, 256, 0, stream>>>(emb, E, Ebf);
  prep_pairs_kernel<<<PN / 256, 256, 0, stream>>>(pairs, pcnt, parts);
  prep_compact_kernel<<<BN / 256, 256, 0, stream>>>(pcnt, rlist, cnt);
  pos_kernel<<<PN / 4, 256, 0, stream>>>(E, pairs, pos);
  gemm_code_kernel<<<dim3(BN / 128, BN / 128), 256, 0, stream>>>(Ebf, rlist, cnt, expc4);
  row_stats4_kernel<<<BN / 4, 256, 0, stream>>>(expc4, rlist, cnt, pcnt, parts, S);
  finale_kernel<<<1, 256, 0, stream>>>(pos, pairs, S, out);
}